// Round 6
// baseline (226.261 us; speedup 1.0000x reference)
//
#include <hip/hip_runtime.h>
#include <hip/hip_bf16.h>

// spatial_attention: out = [softmax_weights | H] @ Wcat^T + bias
//   K0 : Wbf = bf16(W)                                   (512 KB)
//   K1 : P1T[b][d][j] = bf16( (H W1^T)[j][d] )           (32 MB, transposed)
//   K2 : fused, BARRIER-FREE GEMM — weight numerators in A-frag registers,
//        B-fragments loaded straight from global (P1T/Wbf are L2/L3-resident),
//        mid-kernel row-scale of acc, then H@W2 from global, +bias.
// Workspace: Wbf 512KB @0 ; P1T 32MB @1MB  (33MB total)

typedef __attribute__((ext_vector_type(4))) float  f32x4;
typedef __attribute__((ext_vector_type(8))) short  bf16x8;
typedef __attribute__((ext_vector_type(4))) short  bf16x4;

#define EPSC 1e-14f

__device__ __forceinline__ short f2bf(float v) {
  __hip_bfloat16 h = __float2bfloat16(v);
  return *reinterpret_cast<short*>(&h);
}

// ---------------- K0: W fp32 -> bf16, same layout (256 x 512) ----------------
__global__ void k0_pack(const float* __restrict__ W, short* __restrict__ Wbf) {
  int idx = blockIdx.x * 256 + threadIdx.x;
  f32x4 v = *(const f32x4*)(W + (size_t)idx * 4);
  bf16x4 pk;
  pk[0] = f2bf(v[0]); pk[1] = f2bf(v[1]); pk[2] = f2bf(v[2]); pk[3] = f2bf(v[3]);
  *(bf16x4*)(Wbf + (size_t)idx * 4) = pk;
}

// ---------------- K1: P1T = (H @ W1^T)^T, grid 1024 (64 j-rows), block 512 ----------------
__global__ __launch_bounds__(512) void k1_proj(
    const float* __restrict__ H, const short* __restrict__ Wbf,
    short* __restrict__ P1T) {
  extern __shared__ char sm[];
  char* sA = sm;                 // 64 rows x 64 k bf16, 144B stride
  char* sB = sm + 9216;          // 256 d x 64 k bf16, 144B stride
  const int t  = threadIdx.x;
  const int n0 = blockIdx.x * 64;
  const int b  = n0 >> 8;
  const int jb = n0 & 255;

  const int wid = t >> 6, l = t & 63;
  const int wn = wid >> 2, wc = wid & 3;
  const int lr = l & 15, lg = l >> 4;
  f32x4 acc[2][4] = {};

  for (int kk = 0; kk < 256; kk += 64) {
    __syncthreads();
    #pragma unroll
    for (int p = 0; p < 2; ++p) {
      int q = t + 512 * p;
      int j = q >> 4, seg = q & 15;
      f32x4 hv = *(const f32x4*)(H + ((size_t)(n0 + j)) * 256 + kk + seg * 4);
      bf16x4 pk;
      pk[0] = f2bf(hv[0]); pk[1] = f2bf(hv[1]); pk[2] = f2bf(hv[2]); pk[3] = f2bf(hv[3]);
      *(bf16x4*)(sA + j * 144 + seg * 8) = pk;
    }
    #pragma unroll
    for (int p = 0; p < 4; ++p) {
      int z = t + 512 * p;
      int d = z >> 3, s = z & 7;
      bf16x8 v = *(const bf16x8*)(Wbf + (size_t)d * 512 + kk + s * 8);
      *(bf16x8*)(sB + d * 144 + s * 16) = v;
    }
    __syncthreads();
    #pragma unroll
    for (int sub = 0; sub < 2; ++sub) {
      bf16x8 a[2], bb[4];
      #pragma unroll
      for (int m = 0; m < 2; ++m) {
        int row = wn * 32 + m * 16 + lr;
        a[m] = *(const bf16x8*)(sA + row * 144 + sub * 64 + lg * 16);
      }
      #pragma unroll
      for (int f = 0; f < 4; ++f) {
        int d = wc * 64 + f * 16 + lr;
        bb[f] = *(const bf16x8*)(sB + d * 144 + sub * 64 + lg * 16);
      }
      #pragma unroll
      for (int m = 0; m < 2; ++m) {
        #pragma unroll
        for (int f = 0; f < 4; ++f)
          acc[m][f] = __builtin_amdgcn_mfma_f32_16x16x32_bf16(a[m], bb[f], acc[m][f], 0, 0, 0);
      }
    }
  }

  #pragma unroll
  for (int m = 0; m < 2; ++m) {
    int jl = wn * 32 + m * 16 + lg * 4;
    #pragma unroll
    for (int f = 0; f < 4; ++f) {
      int d = wc * 64 + f * 16 + lr;
      f32x4 v = acc[m][f];
      bf16x4 pk;
      pk[0] = f2bf(v[0]); pk[1] = f2bf(v[1]); pk[2] = f2bf(v[2]); pk[3] = f2bf(v[3]);
      *(bf16x4*)(P1T + (size_t)b * 65536 + (size_t)d * 256 + jb + jl) = pk;
    }
  }
}

// ---------------- K2 fused, barrier-free: grid 1024 (b = blk>>2, i0 = (blk&3)*64) ----------------
// block 256 = 4 waves; each wave owns 16 rows x 256 d (acc[16]).
// B-fragments read directly from global (P1T / Wbf are L2/L3 resident).
// LDS: dom 20736 ; mask 1024 ; bias 1024 = 22784 B. One sync after staging, none after.
__global__ __launch_bounds__(256) void k2_fused(
    const float* __restrict__ dist, const float* __restrict__ bear,
    const float* __restrict__ head, const float* __restrict__ seqmask,
    const float* __restrict__ domain, const short* __restrict__ P1T,
    const short* __restrict__ Wbf, const float* __restrict__ H,
    const float* __restrict__ bias, float* __restrict__ out) {
  extern __shared__ char sm[];
  float* sDom  = (float*)sm;
  float* sMask = (float*)(sm + 20736);
  float* sBias = (float*)(sm + 21760);
  const int t  = threadIdx.x;
  const int b  = blockIdx.x >> 2;
  const int i0 = (blockIdx.x & 3) * 64;

  for (int x = t; x < 72 * 72; x += 256) sDom[x] = domain[x];
  sMask[t] = seqmask[b * 256 + t];
  sBias[t] = bias[t];
  __syncthreads();                              // the ONLY barrier

  const int wid = t >> 6, l = t & 63;
  const int lr = l & 15, lg = l >> 4;
  const int i  = i0 + wid * 16 + lr;            // this thread's weight row
  const float mI = sMask[i];
  const size_t base = ((size_t)b * 256 + i) * 256;
  const short* __restrict__ P1b = P1T + (size_t)b * 65536;

  f32x4 acc[16] = {};
  float rs = 0.f;

  // ---- first half: weights (A-frag regs) @ P1T (global, L2-hot), 4 chunks of K=64 ----
  for (int c = 0; c < 4; ++c) {
    const int kk = c * 64;
    #pragma unroll
    for (int sub = 0; sub < 2; ++sub) {
      const int k0 = kk + sub * 32 + lg * 8;
      f32x4 d0 = *(const f32x4*)(dist + base + k0);
      f32x4 d1 = *(const f32x4*)(dist + base + k0 + 4);
      f32x4 b0 = *(const f32x4*)(bear + base + k0);
      f32x4 b1 = *(const f32x4*)(bear + base + k0 + 4);
      f32x4 h0 = *(const f32x4*)(head + base + k0);
      f32x4 h1 = *(const f32x4*)(head + base + k0 + 4);
      f32x4 m0 = *(const f32x4*)(sMask + k0);
      f32x4 m1 = *(const f32x4*)(sMask + k0 + 4);
      bf16x8 pk;
      #pragma unroll
      for (int e = 0; e < 4; ++e) {
        float f1 = fminf(fmaxf(floorf((h0[e] + 2.5f) * 0.2f), 0.f), 71.f);
        float f2 = fminf(fmaxf(floorf((b0[e] + 2.5f) * 0.2f), 0.f), 71.f);
        float wv = fmaxf(sDom[(int)(f1 * 72.f + f2)] - d0[e], 0.f);
        bool valid = (i != k0 + e) && (mI != 0.f) && (m0[e] != 0.f);
        float ex = (wv > 0.f) ? __expf(wv) : 0.f;
        ex = valid ? ex : 0.f;
        rs += ex;
        pk[e] = f2bf(valid ? (ex + EPSC) : 0.f);
      }
      #pragma unroll
      for (int e = 0; e < 4; ++e) {
        float f1 = fminf(fmaxf(floorf((h1[e] + 2.5f) * 0.2f), 0.f), 71.f);
        float f2 = fminf(fmaxf(floorf((b1[e] + 2.5f) * 0.2f), 0.f), 71.f);
        float wv = fmaxf(sDom[(int)(f1 * 72.f + f2)] - d1[e], 0.f);
        bool valid = (i != k0 + 4 + e) && (mI != 0.f) && (m1[e] != 0.f);
        float ex = (wv > 0.f) ? __expf(wv) : 0.f;
        ex = valid ? ex : 0.f;
        rs += ex;
        pk[4 + e] = f2bf(valid ? (ex + EPSC) : 0.f);
      }
      // MFMA against P1T directly from global
      const short* bp = P1b + kk + sub * 32 + lg * 8;
      #pragma unroll
      for (int n = 0; n < 16; ++n) {
        bf16x8 bb = *(const bf16x8*)(bp + (size_t)(n * 16 + lr) * 256);
        acc[n] = __builtin_amdgcn_mfma_f32_16x16x32_bf16(pk, bb, acc[n], 0, 0, 0);
      }
    }
  }

  // ---- row-sum reduce (across lg lanes) and scale accumulators ----
  rs += __shfl_xor(rs, 16, 64);
  rs += __shfl_xor(rs, 32, 64);
  const float scale = 1.0f / (rs + 257.0f * EPSC);   // lane lr holds scale for row lr
  float srow[4];
  #pragma unroll
  for (int r = 0; r < 4; ++r) srow[r] = __shfl(scale, lg * 4 + r, 64);
  #pragma unroll
  for (int n = 0; n < 16; ++n) {
    acc[n][0] *= srow[0]; acc[n][1] *= srow[1];
    acc[n][2] *= srow[2]; acc[n][3] *= srow[3];
  }

  // ---- second half: bf16(H) @ W2 (k = 256..511), straight from global ----
  for (int c = 0; c < 4; ++c) {
    const int kk = c * 64;
    #pragma unroll
    for (int sub = 0; sub < 2; ++sub) {
      const int k0 = kk + sub * 32 + lg * 8;
      f32x4 x0 = *(const f32x4*)(H + base + k0);
      f32x4 x1 = *(const f32x4*)(H + base + k0 + 4);
      bf16x8 av;
      av[0] = f2bf(x0[0]); av[1] = f2bf(x0[1]); av[2] = f2bf(x0[2]); av[3] = f2bf(x0[3]);
      av[4] = f2bf(x1[0]); av[5] = f2bf(x1[1]); av[6] = f2bf(x1[2]); av[7] = f2bf(x1[3]);
      const short* bp = Wbf + 256 + kk + sub * 32 + lg * 8;
      #pragma unroll
      for (int n = 0; n < 16; ++n) {
        bf16x8 bb = *(const bf16x8*)(bp + (size_t)(n * 16 + lr) * 512);
        acc[n] = __builtin_amdgcn_mfma_f32_16x16x32_bf16(av, bb, acc[n], 0, 0, 0);
      }
    }
  }

  // ---- epilogue: + bias, store ----
  #pragma unroll
  for (int n = 0; n < 16; ++n) {
    int d = n * 16 + lr;
    float bs = sBias[d];
    #pragma unroll
    for (int r = 0; r < 4; ++r) {
      int row = i0 + wid * 16 + lg * 4 + r;
      out[((size_t)b * 256 + row) * 256 + d] = acc[n][r] + bs;
    }
  }
}

extern "C" void kernel_launch(void* const* d_in, const int* in_sizes, int n_in,
                              void* d_out, int out_size, void* d_ws, size_t ws_size,
                              hipStream_t stream) {
  const float* hidden  = (const float*)d_in[0];
  const float* dist    = (const float*)d_in[1];
  const float* bear    = (const float*)d_in[2];
  const float* head    = (const float*)d_in[3];
  const float* seqmask = (const float*)d_in[4];
  const float* domain  = (const float*)d_in[5];
  const float* W       = (const float*)d_in[6];
  const float* bias    = (const float*)d_in[7];
  float* out = (float*)d_out;

  char* ws = (char*)d_ws;
  short* Wbf = (short*)ws;                                   // 512 KB
  short* P1T = (short*)(ws + (1u << 20));                    // 32 MB

  k0_pack<<<128, 256, 0, stream>>>(W, Wbf);
  k1_proj<<<1024, 512, 46080, stream>>>(hidden, Wbf, P1T);
  k2_fused<<<1024, 256, 22784, stream>>>(dist, bear, head, seqmask, domain,
                                         P1T, Wbf, hidden, bias, out);
}

// Round 7
// 216.736 us; speedup vs baseline: 1.0440x; 1.0440x over previous
//
#include <hip/hip_runtime.h>
#include <hip/hip_bf16.h>

// spatial_attention: out = [softmax_weights | H] @ Wcat^T + bias
//   K0 : Wbf = bf16(W)                                   (512 KB)
//   K1 : P1T[b][d][j] = bf16( (H W1^T)[j][d] )           (32 MB, transposed)
//   K2 : fused, d-split: block = (b, d-half). sB = P1T half staged ONCE (64KB LDS);
//        weights computed in A-frag regs; ZERO barriers in the K-loop; mid-kernel
//        row-scale; restage sB with W2 half; H@W2; +bias.
// Workspace: Wbf 512KB @0 ; P1T 32MB @1MB  (33MB total)

typedef __attribute__((ext_vector_type(4))) float  f32x4;
typedef __attribute__((ext_vector_type(8))) short  bf16x8;
typedef __attribute__((ext_vector_type(4))) short  bf16x4;

#define EPSC 1e-14f

__device__ __forceinline__ short f2bf(float v) {
  __hip_bfloat16 h = __float2bfloat16(v);
  return *reinterpret_cast<short*>(&h);
}

// ---------------- K0: W fp32 -> bf16, same layout (256 x 512) ----------------
__global__ void k0_pack(const float* __restrict__ W, short* __restrict__ Wbf) {
  int idx = blockIdx.x * 256 + threadIdx.x;
  f32x4 v = *(const f32x4*)(W + (size_t)idx * 4);
  bf16x4 pk;
  pk[0] = f2bf(v[0]); pk[1] = f2bf(v[1]); pk[2] = f2bf(v[2]); pk[3] = f2bf(v[3]);
  *(bf16x4*)(Wbf + (size_t)idx * 4) = pk;
}

// ---------------- K1: P1T = (H @ W1^T)^T, grid 1024 (64 j-rows), block 512 ----------------
__global__ __launch_bounds__(512) void k1_proj(
    const float* __restrict__ H, const short* __restrict__ Wbf,
    short* __restrict__ P1T) {
  extern __shared__ char sm[];
  char* sA = sm;                 // 64 rows x 64 k bf16, 144B stride
  char* sB = sm + 9216;          // 256 d x 64 k bf16, 144B stride
  const int t  = threadIdx.x;
  const int n0 = blockIdx.x * 64;
  const int b  = n0 >> 8;
  const int jb = n0 & 255;

  const int wid = t >> 6, l = t & 63;
  const int wn = wid >> 2, wc = wid & 3;
  const int lr = l & 15, lg = l >> 4;
  f32x4 acc[2][4] = {};

  for (int kk = 0; kk < 256; kk += 64) {
    __syncthreads();
    #pragma unroll
    for (int p = 0; p < 2; ++p) {
      int q = t + 512 * p;
      int j = q >> 4, seg = q & 15;
      f32x4 hv = *(const f32x4*)(H + ((size_t)(n0 + j)) * 256 + kk + seg * 4);
      bf16x4 pk;
      pk[0] = f2bf(hv[0]); pk[1] = f2bf(hv[1]); pk[2] = f2bf(hv[2]); pk[3] = f2bf(hv[3]);
      *(bf16x4*)(sA + j * 144 + seg * 8) = pk;
    }
    #pragma unroll
    for (int p = 0; p < 4; ++p) {
      int z = t + 512 * p;
      int d = z >> 3, s = z & 7;
      bf16x8 v = *(const bf16x8*)(Wbf + (size_t)d * 512 + kk + s * 8);
      *(bf16x8*)(sB + d * 144 + s * 16) = v;
    }
    __syncthreads();
    #pragma unroll
    for (int sub = 0; sub < 2; ++sub) {
      bf16x8 a[2], bb[4];
      #pragma unroll
      for (int m = 0; m < 2; ++m) {
        int row = wn * 32 + m * 16 + lr;
        a[m] = *(const bf16x8*)(sA + row * 144 + sub * 64 + lg * 16);
      }
      #pragma unroll
      for (int f = 0; f < 4; ++f) {
        int d = wc * 64 + f * 16 + lr;
        bb[f] = *(const bf16x8*)(sB + d * 144 + sub * 64 + lg * 16);
      }
      #pragma unroll
      for (int m = 0; m < 2; ++m) {
        #pragma unroll
        for (int f = 0; f < 4; ++f)
          acc[m][f] = __builtin_amdgcn_mfma_f32_16x16x32_bf16(a[m], bb[f], acc[m][f], 0, 0, 0);
      }
    }
  }

  #pragma unroll
  for (int m = 0; m < 2; ++m) {
    int jl = wn * 32 + m * 16 + lg * 4;
    #pragma unroll
    for (int f = 0; f < 4; ++f) {
      int d = wc * 64 + f * 16 + lr;
      f32x4 v = acc[m][f];
      bf16x4 pk;
      pk[0] = f2bf(v[0]); pk[1] = f2bf(v[1]); pk[2] = f2bf(v[2]); pk[3] = f2bf(v[3]);
      *(bf16x4*)(P1T + (size_t)b * 65536 + (size_t)d * 256 + jb + jl) = pk;
    }
  }
}

// weight-numerator A-fragment for one row, one k-slice of 8
__device__ __forceinline__ bf16x8 wfrag(
    const float* __restrict__ dist, const float* __restrict__ bear,
    const float* __restrict__ head, const float* __restrict__ domain,
    const f32x4& mk0, const f32x4& mk1,
    size_t base, int k0, int i, float mI, float& rs) {
  f32x4 d0 = *(const f32x4*)(dist + base + k0);
  f32x4 d1 = *(const f32x4*)(dist + base + k0 + 4);
  f32x4 b0 = *(const f32x4*)(bear + base + k0);
  f32x4 b1 = *(const f32x4*)(bear + base + k0 + 4);
  f32x4 h0 = *(const f32x4*)(head + base + k0);
  f32x4 h1 = *(const f32x4*)(head + base + k0 + 4);
  bf16x8 pk;
  #pragma unroll
  for (int e = 0; e < 4; ++e) {
    float f1 = fminf(fmaxf(floorf((h0[e] + 2.5f) * 0.2f), 0.f), 71.f);
    float f2 = fminf(fmaxf(floorf((b0[e] + 2.5f) * 0.2f), 0.f), 71.f);
    float wv = fmaxf(domain[(int)(f1 * 72.f + f2)] - d0[e], 0.f);
    bool valid = (i != k0 + e) && (mI != 0.f) && (mk0[e] != 0.f);
    float ex = (wv > 0.f) ? __expf(wv) : 0.f;
    ex = valid ? ex : 0.f;
    rs += ex;
    pk[e] = f2bf(valid ? (ex + EPSC) : 0.f);
  }
  #pragma unroll
  for (int e = 0; e < 4; ++e) {
    float f1 = fminf(fmaxf(floorf((h1[e] + 2.5f) * 0.2f), 0.f), 71.f);
    float f2 = fminf(fmaxf(floorf((b1[e] + 2.5f) * 0.2f), 0.f), 71.f);
    float wv = fmaxf(domain[(int)(f1 * 72.f + f2)] - d1[e], 0.f);
    bool valid = (i != k0 + 4 + e) && (mI != 0.f) && (mk1[e] != 0.f);
    float ex = (wv > 0.f) ? __expf(wv) : 0.f;
    ex = valid ? ex : 0.f;
    rs += ex;
    pk[4 + e] = f2bf(valid ? (ex + EPSC) : 0.f);
  }
  return pk;
}

// ---------------- K2 fused, d-split: grid 512 (b = blk>>1, D0 = (blk&1)*128) ----------------
// block 512 = 8 waves; wave owns 32 rows x 128 d (acc[2][8]).
// LDS: sB [128 dd][528B] = 67584 B. Three barriers total; K-loops barrier-free.
__global__ __launch_bounds__(512, 4) void k2_fused(
    const float* __restrict__ dist, const float* __restrict__ bear,
    const float* __restrict__ head, const float* __restrict__ seqmask,
    const float* __restrict__ domain, const short* __restrict__ P1T,
    const short* __restrict__ Wbf, const float* __restrict__ H,
    const float* __restrict__ bias, float* __restrict__ out) {
  extern __shared__ char sm[];
  char* sB = sm;                                // [128 dd][256 k] bf16, 528B stride
  const int t  = threadIdx.x;
  const int b  = blockIdx.x >> 1;
  const int D0 = (blockIdx.x & 1) * 128;

  // ---- stage P1T d-half, once ----
  #pragma unroll
  for (int p = 0; p < 8; ++p) {
    int z = t + 512 * p;                        // 0..4095 : dd = z>>5, s = z&31
    int dd = z >> 5, s = z & 31;
    bf16x8 v = *(const bf16x8*)(P1T + (size_t)b * 65536 + (size_t)(D0 + dd) * 256 + s * 8);
    *(bf16x8*)(sB + dd * 528 + s * 16) = v;
  }
  __syncthreads();                              // barrier 1

  const int wid = t >> 6, l = t & 63;
  const int lr = l & 15, lg = l >> 4;
  const int R0 = wid * 32;
  const int i0r = R0 + lr;                      // m=0 row
  const int i1r = R0 + 16 + lr;                 // m=1 row
  const float mI0 = seqmask[b * 256 + i0r];
  const float mI1 = seqmask[b * 256 + i1r];
  const size_t base0 = ((size_t)b * 256 + i0r) * 256;
  const size_t base1 = ((size_t)b * 256 + i1r) * 256;

  f32x4 acc[2][8] = {};
  float rs0 = 0.f, rs1 = 0.f;

  // ---- GEMM1: weights (regs) @ P1T (LDS), no barriers ----
  #pragma unroll 2
  for (int sidx = 0; sidx < 8; ++sidx) {
    const int k0 = sidx * 32 + lg * 8;
    f32x4 mk0 = *(const f32x4*)(seqmask + b * 256 + k0);
    f32x4 mk1 = *(const f32x4*)(seqmask + b * 256 + k0 + 4);
    bf16x8 pk0 = wfrag(dist, bear, head, domain, mk0, mk1, base0, k0, i0r, mI0, rs0);
    bf16x8 pk1 = wfrag(dist, bear, head, domain, mk0, mk1, base1, k0, i1r, mI1, rs1);
    #pragma unroll
    for (int n = 0; n < 8; ++n) {
      bf16x8 bb = *(const bf16x8*)(sB + (n * 16 + lr) * 528 + k0 * 2);
      acc[0][n] = __builtin_amdgcn_mfma_f32_16x16x32_bf16(pk0, bb, acc[0][n], 0, 0, 0);
      acc[1][n] = __builtin_amdgcn_mfma_f32_16x16x32_bf16(pk1, bb, acc[1][n], 0, 0, 0);
    }
  }

  // ---- row-sum reduce (across lg) and scale accumulators ----
  rs0 += __shfl_xor(rs0, 16, 64); rs0 += __shfl_xor(rs0, 32, 64);
  rs1 += __shfl_xor(rs1, 16, 64); rs1 += __shfl_xor(rs1, 32, 64);
  const float sc0 = 1.0f / (rs0 + 257.0f * EPSC);
  const float sc1 = 1.0f / (rs1 + 257.0f * EPSC);
  float srow[2][4];
  #pragma unroll
  for (int r = 0; r < 4; ++r) {
    srow[0][r] = __shfl(sc0, lg * 4 + r, 64);
    srow[1][r] = __shfl(sc1, lg * 4 + r, 64);
  }
  #pragma unroll
  for (int m = 0; m < 2; ++m)
    #pragma unroll
    for (int n = 0; n < 8; ++n) {
      acc[m][n][0] *= srow[m][0]; acc[m][n][1] *= srow[m][1];
      acc[m][n][2] *= srow[m][2]; acc[m][n][3] *= srow[m][3];
    }

  // ---- restage sB with W2 d-half (k = 256..511) ----
  __syncthreads();                              // barrier 2: all waves done with P1T
  #pragma unroll
  for (int p = 0; p < 8; ++p) {
    int z = t + 512 * p;
    int dd = z >> 5, s = z & 31;
    bf16x8 v = *(const bf16x8*)(Wbf + (size_t)(D0 + dd) * 512 + 256 + s * 8);
    *(bf16x8*)(sB + dd * 528 + s * 16) = v;
  }
  __syncthreads();                              // barrier 3

  // ---- GEMM2: bf16(H) @ W2 (LDS), no barriers ----
  #pragma unroll 2
  for (int sidx = 0; sidx < 8; ++sidx) {
    const int k0 = sidx * 32 + lg * 8;
    f32x4 x0 = *(const f32x4*)(H + base0 + k0);
    f32x4 x1 = *(const f32x4*)(H + base0 + k0 + 4);
    f32x4 y0 = *(const f32x4*)(H + base1 + k0);
    f32x4 y1 = *(const f32x4*)(H + base1 + k0 + 4);
    bf16x8 av0, av1;
    av0[0] = f2bf(x0[0]); av0[1] = f2bf(x0[1]); av0[2] = f2bf(x0[2]); av0[3] = f2bf(x0[3]);
    av0[4] = f2bf(x1[0]); av0[5] = f2bf(x1[1]); av0[6] = f2bf(x1[2]); av0[7] = f2bf(x1[3]);
    av1[0] = f2bf(y0[0]); av1[1] = f2bf(y0[1]); av1[2] = f2bf(y0[2]); av1[3] = f2bf(y0[3]);
    av1[4] = f2bf(y1[0]); av1[5] = f2bf(y1[1]); av1[6] = f2bf(y1[2]); av1[7] = f2bf(y1[3]);
    #pragma unroll
    for (int n = 0; n < 8; ++n) {
      bf16x8 bb = *(const bf16x8*)(sB + (n * 16 + lr) * 528 + k0 * 2);
      acc[0][n] = __builtin_amdgcn_mfma_f32_16x16x32_bf16(av0, bb, acc[0][n], 0, 0, 0);
      acc[1][n] = __builtin_amdgcn_mfma_f32_16x16x32_bf16(av1, bb, acc[1][n], 0, 0, 0);
    }
  }

  // ---- epilogue: + bias, store ----
  #pragma unroll
  for (int n = 0; n < 8; ++n) {
    int d = D0 + n * 16 + lr;
    float bs = bias[d];
    #pragma unroll
    for (int m = 0; m < 2; ++m) {
      #pragma unroll
      for (int r = 0; r < 4; ++r) {
        int row = R0 + m * 16 + lg * 4 + r;
        out[((size_t)b * 256 + row) * 256 + d] = acc[m][n][r] + bs;
      }
    }
  }
}

extern "C" void kernel_launch(void* const* d_in, const int* in_sizes, int n_in,
                              void* d_out, int out_size, void* d_ws, size_t ws_size,
                              hipStream_t stream) {
  const float* hidden  = (const float*)d_in[0];
  const float* dist    = (const float*)d_in[1];
  const float* bear    = (const float*)d_in[2];
  const float* head    = (const float*)d_in[3];
  const float* seqmask = (const float*)d_in[4];
  const float* domain  = (const float*)d_in[5];
  const float* W       = (const float*)d_in[6];
  const float* bias    = (const float*)d_in[7];
  float* out = (float*)d_out;

  char* ws = (char*)d_ws;
  short* Wbf = (short*)ws;                                   // 512 KB
  short* P1T = (short*)(ws + (1u << 20));                    // 32 MB

  k0_pack<<<128, 256, 0, stream>>>(W, Wbf);
  k1_proj<<<1024, 512, 46080, stream>>>(hidden, Wbf, P1T);
  k2_fused<<<512, 512, 67584, stream>>>(dist, bear, head, seqmask, domain,
                                        P1T, Wbf, hidden, bias, out);
}

// Round 8
// 137.515 us; speedup vs baseline: 1.6454x; 1.5761x over previous
//
#include <hip/hip_runtime.h>
#include <hip/hip_bf16.h>

// spatial_attention: out = [softmax_weights | H] @ Wcat^T + bias
//   Key fact: reference builds domain = full(2.0) -> domain[i1,i2] is CONSTANT.
//   k0_check verifies uniformity at runtime -> fast path needs NO gathers and
//   never reads bearing/heading at all: w = relu(dval - dist).
//   K0 : Wbf = bf16(W); k0_check: {dval, uniform} flag
//   K1 : P1T[b][d][j] = bf16( (H W1^T)[j][d] )   (32 MB, transposed)
//   K2 : fused row-split GEMM, double-buffered sB, prefetch of next chunk's
//        B-tile AND A-operands (dist / H) before current MFMAs; 1 barrier/chunk.
// Workspace: Wbf 512KB @0 ; flag @512KB ; P1T 32MB @1MB

typedef __attribute__((ext_vector_type(4))) float  f32x4;
typedef __attribute__((ext_vector_type(8))) short  bf16x8;
typedef __attribute__((ext_vector_type(4))) short  bf16x4;

#define EPSC 1e-14f

__device__ __forceinline__ short f2bf(float v) {
  __hip_bfloat16 h = __float2bfloat16(v);
  return *reinterpret_cast<short*>(&h);
}

// ---------------- K0: W fp32 -> bf16 ----------------
__global__ void k0_pack(const float* __restrict__ W, short* __restrict__ Wbf) {
  int idx = blockIdx.x * 256 + threadIdx.x;
  f32x4 v = *(const f32x4*)(W + (size_t)idx * 4);
  bf16x4 pk;
  pk[0] = f2bf(v[0]); pk[1] = f2bf(v[1]); pk[2] = f2bf(v[2]); pk[3] = f2bf(v[3]);
  *(bf16x4*)(Wbf + (size_t)idx * 4) = pk;
}

// ---------------- K0b: domain uniformity check ----------------
__global__ void k0_check(const float* __restrict__ domain, float* __restrict__ flag) {
  __shared__ int s_ok[4];
  const int t = threadIdx.x;
  float v0 = domain[0];
  bool ok = true;
  for (int x = t; x < 72 * 72; x += 256) ok = ok && (domain[x] == v0);
  unsigned long long m = __ballot(ok);
  if ((t & 63) == 0) s_ok[t >> 6] = (m == ~0ull) ? 1 : 0;
  __syncthreads();
  if (t == 0) {
    flag[0] = v0;
    flag[1] = (s_ok[0] && s_ok[1] && s_ok[2] && s_ok[3]) ? 1.f : 0.f;
  }
}

// ---------------- K1: P1T = (H @ W1^T)^T, grid 1024, block 512 ----------------
__global__ __launch_bounds__(512) void k1_proj(
    const float* __restrict__ H, const short* __restrict__ Wbf,
    short* __restrict__ P1T) {
  extern __shared__ char sm[];
  char* sA = sm;                 // 64 rows x 64 k bf16, 144B stride
  char* sB = sm + 9216;          // 256 d x 64 k bf16, 144B stride
  const int t  = threadIdx.x;
  const int n0 = blockIdx.x * 64;
  const int b  = n0 >> 8;
  const int jb = n0 & 255;

  const int wid = t >> 6, l = t & 63;
  const int wn = wid >> 2, wc = wid & 3;
  const int lr = l & 15, lg = l >> 4;
  f32x4 acc[2][4] = {};

  for (int kk = 0; kk < 256; kk += 64) {
    __syncthreads();
    #pragma unroll
    for (int p = 0; p < 2; ++p) {
      int q = t + 512 * p;
      int j = q >> 4, seg = q & 15;
      f32x4 hv = *(const f32x4*)(H + ((size_t)(n0 + j)) * 256 + kk + seg * 4);
      bf16x4 pk;
      pk[0] = f2bf(hv[0]); pk[1] = f2bf(hv[1]); pk[2] = f2bf(hv[2]); pk[3] = f2bf(hv[3]);
      *(bf16x4*)(sA + j * 144 + seg * 8) = pk;
    }
    #pragma unroll
    for (int p = 0; p < 4; ++p) {
      int z = t + 512 * p;
      int d = z >> 3, s = z & 7;
      bf16x8 v = *(const bf16x8*)(Wbf + (size_t)d * 512 + kk + s * 8);
      *(bf16x8*)(sB + d * 144 + s * 16) = v;
    }
    __syncthreads();
    #pragma unroll
    for (int sub = 0; sub < 2; ++sub) {
      bf16x8 a[2], bb[4];
      #pragma unroll
      for (int m = 0; m < 2; ++m) {
        int row = wn * 32 + m * 16 + lr;
        a[m] = *(const bf16x8*)(sA + row * 144 + sub * 64 + lg * 16);
      }
      #pragma unroll
      for (int f = 0; f < 4; ++f) {
        int d = wc * 64 + f * 16 + lr;
        bb[f] = *(const bf16x8*)(sB + d * 144 + sub * 64 + lg * 16);
      }
      #pragma unroll
      for (int m = 0; m < 2; ++m) {
        #pragma unroll
        for (int f = 0; f < 4; ++f)
          acc[m][f] = __builtin_amdgcn_mfma_f32_16x16x32_bf16(a[m], bb[f], acc[m][f], 0, 0, 0);
      }
    }
  }

  #pragma unroll
  for (int m = 0; m < 2; ++m) {
    int jl = wn * 32 + m * 16 + lg * 4;
    #pragma unroll
    for (int f = 0; f < 4; ++f) {
      int d = wc * 64 + f * 16 + lr;
      f32x4 v = acc[m][f];
      bf16x4 pk;
      pk[0] = f2bf(v[0]); pk[1] = f2bf(v[1]); pk[2] = f2bf(v[2]); pk[3] = f2bf(v[3]);
      *(bf16x4*)(P1T + (size_t)b * 65536 + (size_t)d * 256 + jb + jl) = pk;
    }
  }
}

// ---------------- K2 fused: grid 512 (b = blk>>1, i0 = (blk&1)*128), block 512 ----------------
// 8 waves, wave owns 16 rows (wid*16+lr) x 256 d (acc[16]). Double-buffered sB,
// next-chunk B-tile + A-operands prefetched before current MFMAs. 1 barrier/chunk.
// LDS: sB0 36864 ; sB1 36864 ; mask 1024 ; bias 1024 = 75776 B -> 2 blocks/CU
__global__ __launch_bounds__(512, 4) void k2_fused(
    const float* __restrict__ dist, const float* __restrict__ bear,
    const float* __restrict__ head, const float* __restrict__ seqmask,
    const float* __restrict__ domain, const short* __restrict__ P1T,
    const short* __restrict__ Wbf, const float* __restrict__ H,
    const float* __restrict__ bias, const float* __restrict__ uflag,
    float* __restrict__ out) {
  extern __shared__ char sm[];
  char*  sB0   = sm;
  char*  sB1   = sm + 36864;
  float* sMask = (float*)(sm + 73728);
  float* sBias = (float*)(sm + 74752);
  const int t  = threadIdx.x;
  const int b  = blockIdx.x >> 1;
  const int i0 = (blockIdx.x & 1) * 128;

  const int wid = t >> 6, l = t & 63;
  const int lr = l & 15, lg = l >> 4;
  const int i  = i0 + wid * 16 + lr;
  const size_t base = ((size_t)b * 256 + i) * 256;
  const short* __restrict__ P1b = P1T + (size_t)b * 65536;

  const float dval = uflag[0];
  const bool  uni  = uflag[1] != 0.f;

  // ---- prologue: stage chunk 0 (P1T) + this thread's chunk-0 dist slices ----
  {
    bf16x8 st[4];
    #pragma unroll
    for (int p = 0; p < 4; ++p) {
      int z = t + 512 * p;
      st[p] = *(const bf16x8*)(P1b + (size_t)(z >> 3) * 256 + (z & 7) * 8);
    }
    if (t < 256) { sMask[t] = seqmask[b * 256 + t]; sBias[t] = bias[t]; }
    #pragma unroll
    for (int p = 0; p < 4; ++p) {
      int z = t + 512 * p;
      *(bf16x8*)(sB0 + (z >> 3) * 144 + (z & 7) * 16) = st[p];
    }
  }
  f32x4 dA[4];
  #pragma unroll
  for (int su = 0; su < 2; ++su) {
    dA[su * 2]     = *(const f32x4*)(dist + base + su * 32 + lg * 8);
    dA[su * 2 + 1] = *(const f32x4*)(dist + base + su * 32 + lg * 8 + 4);
  }
  __syncthreads();

  const float mI = sMask[i];
  f32x4 acc[16] = {};
  float rs = 0.f;

  // ---- GEMM1: weights (regs) @ P1T, 4 chunks, dbuf, prefetch-next ----
  if (uni) {
    #pragma unroll
    for (int c = 0; c < 4; ++c) {
      char* curB = (c & 1) ? sB1 : sB0;
      char* nxtB = (c & 1) ? sB0 : sB1;
      bf16x8 st[4]; f32x4 dN[4];
      if (c < 3) {
        #pragma unroll
        for (int p = 0; p < 4; ++p) {
          int z = t + 512 * p;
          st[p] = *(const bf16x8*)(P1b + (size_t)(z >> 3) * 256 + (c + 1) * 64 + (z & 7) * 8);
        }
        #pragma unroll
        for (int su = 0; su < 2; ++su) {
          dN[su * 2]     = *(const f32x4*)(dist + base + (c + 1) * 64 + su * 32 + lg * 8);
          dN[su * 2 + 1] = *(const f32x4*)(dist + base + (c + 1) * 64 + su * 32 + lg * 8 + 4);
        }
      } else {
        #pragma unroll
        for (int p = 0; p < 4; ++p) {
          int z = t + 512 * p;
          st[p] = *(const bf16x8*)(Wbf + (size_t)(z >> 3) * 512 + 256 + (z & 7) * 8);
        }
        #pragma unroll
        for (int su = 0; su < 2; ++su) {
          dN[su * 2]     = *(const f32x4*)(H + base + su * 32 + lg * 8);
          dN[su * 2 + 1] = *(const f32x4*)(H + base + su * 32 + lg * 8 + 4);
        }
      }
      #pragma unroll
      for (int sub = 0; sub < 2; ++sub) {
        const int gk = c * 64 + sub * 32 + lg * 8;
        f32x4 m0 = *(const f32x4*)(sMask + gk);
        f32x4 m1 = *(const f32x4*)(sMask + gk + 4);
        f32x4 d0 = dA[sub * 2], d1 = dA[sub * 2 + 1];
        bf16x8 pk;
        #pragma unroll
        for (int e = 0; e < 4; ++e) {
          float wv = fmaxf(dval - d0[e], 0.f);
          bool valid = (i != gk + e) && (mI != 0.f) && (m0[e] != 0.f);
          float ex = (wv > 0.f) ? __expf(wv) : 0.f;
          ex = valid ? ex : 0.f;
          rs += ex;
          pk[e] = f2bf(valid ? (ex + EPSC) : 0.f);
        }
        #pragma unroll
        for (int e = 0; e < 4; ++e) {
          float wv = fmaxf(dval - d1[e], 0.f);
          bool valid = (i != gk + 4 + e) && (mI != 0.f) && (m1[e] != 0.f);
          float ex = (wv > 0.f) ? __expf(wv) : 0.f;
          ex = valid ? ex : 0.f;
          rs += ex;
          pk[4 + e] = f2bf(valid ? (ex + EPSC) : 0.f);
        }
        #pragma unroll
        for (int n = 0; n < 16; ++n) {
          bf16x8 bb = *(const bf16x8*)(curB + (n * 16 + lr) * 144 + sub * 64 + lg * 16);
          acc[n] = __builtin_amdgcn_mfma_f32_16x16x32_bf16(pk, bb, acc[n], 0, 0, 0);
        }
      }
      #pragma unroll
      for (int p = 0; p < 4; ++p) {
        int z = t + 512 * p;
        *(bf16x8*)(nxtB + (z >> 3) * 144 + (z & 7) * 16) = st[p];
      }
      __syncthreads();
      dA[0] = dN[0]; dA[1] = dN[1]; dA[2] = dN[2]; dA[3] = dN[3];
    }
  } else {
    // fallback (non-uniform domain): gather path, correctness only
    #pragma unroll 1
    for (int c = 0; c < 4; ++c) {
      char* curB = (c & 1) ? sB1 : sB0;
      char* nxtB = (c & 1) ? sB0 : sB1;
      bf16x8 st[4]; f32x4 dN[4];
      if (c < 3) {
        for (int p = 0; p < 4; ++p) {
          int z = t + 512 * p;
          st[p] = *(const bf16x8*)(P1b + (size_t)(z >> 3) * 256 + (c + 1) * 64 + (z & 7) * 8);
        }
        for (int su = 0; su < 2; ++su) {
          dN[su * 2]     = *(const f32x4*)(dist + base + (c + 1) * 64 + su * 32 + lg * 8);
          dN[su * 2 + 1] = *(const f32x4*)(dist + base + (c + 1) * 64 + su * 32 + lg * 8 + 4);
        }
      } else {
        for (int p = 0; p < 4; ++p) {
          int z = t + 512 * p;
          st[p] = *(const bf16x8*)(Wbf + (size_t)(z >> 3) * 512 + 256 + (z & 7) * 8);
        }
        for (int su = 0; su < 2; ++su) {
          dN[su * 2]     = *(const f32x4*)(H + base + su * 32 + lg * 8);
          dN[su * 2 + 1] = *(const f32x4*)(H + base + su * 32 + lg * 8 + 4);
        }
      }
      for (int sub = 0; sub < 2; ++sub) {
        const int gk = c * 64 + sub * 32 + lg * 8;
        f32x4 m0 = *(const f32x4*)(sMask + gk);
        f32x4 m1 = *(const f32x4*)(sMask + gk + 4);
        f32x4 b0 = *(const f32x4*)(bear + base + gk);
        f32x4 b1 = *(const f32x4*)(bear + base + gk + 4);
        f32x4 h0 = *(const f32x4*)(head + base + gk);
        f32x4 h1 = *(const f32x4*)(head + base + gk + 4);
        f32x4 d0 = dA[sub * 2], d1 = dA[sub * 2 + 1];
        bf16x8 pk;
        for (int e = 0; e < 4; ++e) {
          float f1 = fminf(fmaxf(floorf((h0[e] + 2.5f) * 0.2f), 0.f), 71.f);
          float f2 = fminf(fmaxf(floorf((b0[e] + 2.5f) * 0.2f), 0.f), 71.f);
          float wv = fmaxf(domain[(int)(f1 * 72.f + f2)] - d0[e], 0.f);
          bool valid = (i != gk + e) && (mI != 0.f) && (m0[e] != 0.f);
          float ex = (wv > 0.f) ? __expf(wv) : 0.f;
          ex = valid ? ex : 0.f;
          rs += ex;
          pk[e] = f2bf(valid ? (ex + EPSC) : 0.f);
        }
        for (int e = 0; e < 4; ++e) {
          float f1 = fminf(fmaxf(floorf((h1[e] + 2.5f) * 0.2f), 0.f), 71.f);
          float f2 = fminf(fmaxf(floorf((b1[e] + 2.5f) * 0.2f), 0.f), 71.f);
          float wv = fmaxf(domain[(int)(f1 * 72.f + f2)] - d1[e], 0.f);
          bool valid = (i != gk + 4 + e) && (mI != 0.f) && (m1[e] != 0.f);
          float ex = (wv > 0.f) ? __expf(wv) : 0.f;
          ex = valid ? ex : 0.f;
          rs += ex;
          pk[4 + e] = f2bf(valid ? (ex + EPSC) : 0.f);
        }
        for (int n = 0; n < 16; ++n) {
          bf16x8 bb = *(const bf16x8*)(curB + (n * 16 + lr) * 144 + sub * 64 + lg * 16);
          acc[n] = __builtin_amdgcn_mfma_f32_16x16x32_bf16(pk, bb, acc[n], 0, 0, 0);
        }
      }
      for (int p = 0; p < 4; ++p) {
        int z = t + 512 * p;
        *(bf16x8*)(nxtB + (z >> 3) * 144 + (z & 7) * 16) = st[p];
      }
      __syncthreads();
      dA[0] = dN[0]; dA[1] = dN[1]; dA[2] = dN[2]; dA[3] = dN[3];
    }
  }

  // ---- row-sum reduce (across lg) and scale accumulators ----
  rs += __shfl_xor(rs, 16, 64);
  rs += __shfl_xor(rs, 32, 64);
  const float scale = 1.0f / (rs + 257.0f * EPSC);
  float srow[4];
  #pragma unroll
  for (int r = 0; r < 4; ++r) srow[r] = __shfl(scale, lg * 4 + r, 64);
  #pragma unroll
  for (int n = 0; n < 16; ++n) {
    acc[n][0] *= srow[0]; acc[n][1] *= srow[1];
    acc[n][2] *= srow[2]; acc[n][3] *= srow[3];
  }

  // ---- GEMM2: bf16(H) @ W2, 4 chunks, dbuf continues (chunk g=4..7) ----
  #pragma unroll
  for (int c = 0; c < 4; ++c) {
    const int g = 4 + c;
    char* curB = (g & 1) ? sB1 : sB0;
    char* nxtB = (g & 1) ? sB0 : sB1;
    bf16x8 st[4]; f32x4 dN[4];
    if (c < 3) {
      #pragma unroll
      for (int p = 0; p < 4; ++p) {
        int z = t + 512 * p;
        st[p] = *(const bf16x8*)(Wbf + (size_t)(z >> 3) * 512 + 256 + (c + 1) * 64 + (z & 7) * 8);
      }
      #pragma unroll
      for (int su = 0; su < 2; ++su) {
        dN[su * 2]     = *(const f32x4*)(H + base + (c + 1) * 64 + su * 32 + lg * 8);
        dN[su * 2 + 1] = *(const f32x4*)(H + base + (c + 1) * 64 + su * 32 + lg * 8 + 4);
      }
    }
    #pragma unroll
    for (int sub = 0; sub < 2; ++sub) {
      f32x4 x0 = dA[sub * 2], x1 = dA[sub * 2 + 1];
      bf16x8 av;
      av[0] = f2bf(x0[0]); av[1] = f2bf(x0[1]); av[2] = f2bf(x0[2]); av[3] = f2bf(x0[3]);
      av[4] = f2bf(x1[0]); av[5] = f2bf(x1[1]); av[6] = f2bf(x1[2]); av[7] = f2bf(x1[3]);
      #pragma unroll
      for (int n = 0; n < 16; ++n) {
        bf16x8 bb = *(const bf16x8*)(curB + (n * 16 + lr) * 144 + sub * 64 + lg * 16);
        acc[n] = __builtin_amdgcn_mfma_f32_16x16x32_bf16(av, bb, acc[n], 0, 0, 0);
      }
    }
    if (c < 3) {
      #pragma unroll
      for (int p = 0; p < 4; ++p) {
        int z = t + 512 * p;
        *(bf16x8*)(nxtB + (z >> 3) * 144 + (z & 7) * 16) = st[p];
      }
      __syncthreads();
      dA[0] = dN[0]; dA[1] = dN[1]; dA[2] = dN[2]; dA[3] = dN[3];
    }
  }

  // ---- epilogue: + bias, store ----
  #pragma unroll
  for (int n = 0; n < 16; ++n) {
    int d = n * 16 + lr;
    float bs = sBias[d];
    #pragma unroll
    for (int r = 0; r < 4; ++r) {
      int row = i0 + wid * 16 + lg * 4 + r;
      out[((size_t)b * 256 + row) * 256 + d] = acc[n][r] + bs;
    }
  }
}

extern "C" void kernel_launch(void* const* d_in, const int* in_sizes, int n_in,
                              void* d_out, int out_size, void* d_ws, size_t ws_size,
                              hipStream_t stream) {
  const float* hidden  = (const float*)d_in[0];
  const float* dist    = (const float*)d_in[1];
  const float* bear    = (const float*)d_in[2];
  const float* head    = (const float*)d_in[3];
  const float* seqmask = (const float*)d_in[4];
  const float* domain  = (const float*)d_in[5];
  const float* W       = (const float*)d_in[6];
  const float* bias    = (const float*)d_in[7];
  float* out = (float*)d_out;

  char* ws = (char*)d_ws;
  short* Wbf  = (short*)ws;                                  // 512 KB
  float* flag = (float*)(ws + 524288);                       // 2 floats
  short* P1T  = (short*)(ws + (1u << 20));                   // 32 MB

  k0_pack<<<128, 256, 0, stream>>>(W, Wbf);
  k0_check<<<1, 256, 0, stream>>>(domain, flag);
  k1_proj<<<1024, 512, 46080, stream>>>(hidden, Wbf, P1T);
  k2_fused<<<512, 512, 75776, stream>>>(dist, bear, head, seqmask, domain,
                                        P1T, Wbf, hidden, bias, flag, out);
}